// Round 13
// baseline (2194.905 us; speedup 1.0000x reference)
//
#include <hip/hip_runtime.h>
#include <math.h>

typedef _Float16 f16;
typedef _Float16 f16x8 __attribute__((ext_vector_type(8)));
typedef float f32x4 __attribute__((ext_vector_type(4)));
typedef unsigned long long u64;
typedef unsigned u32;

union U32H2 { unsigned u; f16 h[2]; };
union UV4H8 { uint4 u; f16x8 h; f16 e[8]; };
union H1 { unsigned short s; f16 h; };

#define LN_EPS 1e-5f

// ---- cache-bypassing (L3-coherent) relaxed agent-scope atomics ----
__device__ __forceinline__ void st_u32g(u32* p, u32 v) {
    __hip_atomic_store(p, v, __ATOMIC_RELAXED, __HIP_MEMORY_SCOPE_AGENT);
}
__device__ __forceinline__ u64 ld_u64g(const u64* p) {
    return __hip_atomic_load(p, __ATOMIC_RELAXED, __HIP_MEMORY_SCOPE_AGENT);
}

// ============================================================================
// init: zero tagged-exchange buffer (every launch — replay safety)
// ============================================================================
__global__ __launch_bounds__(256) void init_ex(u64* p, int n) {
    const int i = blockIdx.x * 256 + threadIdx.x;
    if (i < n) p[i] = 0ull;
}

// ============================================================================
// Phase 0a: pack h-part weights (k<512), GAMMA-FOLDED, into B-fragment order.
//   col = (tile%32)*16 + (lane&15),  k = kf*32 + (lane>>4)*8 + j
// tiles 0..31 = a-gate, 32..63 = g-gate.
// ============================================================================
__global__ __launch_bounds__(256) void pack_wfrags(
    const float* __restrict__ Wa, const float* __restrict__ Wg,
    const float* __restrict__ gamma, uint4* __restrict__ WP)
{
    const int t = blockIdx.x * 256 + threadIdx.x;   // 0..65535
    const int lane = t & 63;
    const int kf = (t >> 6) & 15;
    const int tile = t >> 10;
    const float* W = (tile < 32) ? Wa : Wg;
    const int col = (tile & 31) * 16 + (lane & 15);
    const int k0 = kf * 32 + (lane >> 4) * 8;
    const float* src = W + (size_t)col * 1024 + k0;
    UV4H8 u;
#pragma unroll
    for (int j = 0; j < 8; ++j) u.e[j] = (f16)(src[j] * gamma[k0 + j]);
    WP[t] = u.u;
}

// ============================================================================
// Phase 0a': pack x-part weights (k 512..1023), NO fold, B-fragment order.
// ============================================================================
__global__ __launch_bounds__(256) void pack_wx(
    const float* __restrict__ Wa, const float* __restrict__ Wg,
    uint4* __restrict__ WPx)
{
    const int t = blockIdx.x * 256 + threadIdx.x;   // 0..65535
    const int lane = t & 63;
    const int kf = (t >> 6) & 15;
    const int tile = t >> 10;
    const float* W = (tile < 32) ? Wa : Wg;
    const int col = (tile & 31) * 16 + (lane & 15);
    const int k0 = kf * 32 + (lane >> 4) * 8;
    const float* src = W + (size_t)col * 1024 + 512 + k0;
    UV4H8 u;
#pragma unroll
    for (int j = 0; j < 8; ++j) u.e[j] = (f16)src[j];
    WPx[t] = u.u;
}

// ============================================================================
// Phase 0b: fold constants:
//   Cvec[0][o]=Wa[o]·beta  Cvec[1][o]=Wa[o]·gamma  Cvec[2][o]=Wg[o]·beta
//   Cvec[3][o]=Wg[o]·gamma   (h-part k<512, fp32)
// ============================================================================
__global__ __launch_bounds__(64) void precompute_consts(
    const float* __restrict__ Wa, const float* __restrict__ Wg,
    const float* __restrict__ gamma, const float* __restrict__ beta,
    float* __restrict__ Cvec)
{
    const int o = blockIdx.x;
    const int l = threadIdx.x;
    const float* wa = Wa + (size_t)o * 1024;
    const float* wg = Wg + (size_t)o * 1024;
    float ca = 0.f, ga = 0.f, cg = 0.f, gg = 0.f;
    for (int k = l; k < 512; k += 64) {
        const float bk = beta[k], gk = gamma[k], a = wa[k], g = wg[k];
        ca += a * bk; ga += a * gk; cg += g * bk; gg += g * gk;
    }
#pragma unroll
    for (int m = 1; m < 64; m <<= 1) {
        ca += __shfl_xor(ca, m); ga += __shfl_xor(ga, m);
        cg += __shfl_xor(cg, m); gg += __shfl_xor(gg, m);
    }
    if (l == 0) {
        Cvec[o] = ca; Cvec[512 + o] = ga; Cvec[1024 + o] = cg; Cvec[1536 + o] = gg;
    }
}

// ============================================================================
// Phase 1: precompute P = X @ Wx^T + bias — f16 MFMA (verified round 10).
// ============================================================================
__global__ __launch_bounds__(512) void pgemm16(
    const float* __restrict__ X, const uint4* __restrict__ WPx,
    const float* __restrict__ ba, const float* __restrict__ bg,
    float* __restrict__ Pa, f16* __restrict__ Pgh)
{
    __shared__ f16 As[128 * 64];   // 16 KB, swizzled
    const int tid = threadIdx.x;
    const int wv = tid >> 6, lane = tid & 63;
    const int bid = blockIdx.x;
    const int bn = bid & 7;
    const int bm = bid >> 3;
    const int m0 = bm * 128;
    const int tile = bn * 8 + wv;

    f16x8 Bf[16];
#pragma unroll
    for (int kf = 0; kf < 16; ++kf) {
        UV4H8 uu; uu.u = WPx[(size_t)(tile * 16 + kf) * 64 + lane];
        Bf[kf] = uu.h;
    }
    const int tcol = lane & 15;
    const float bias = (tile < 32) ? ba[tile * 16 + tcol]
                                   : bg[(tile - 32) * 16 + tcol];

    f32x4 acc[8];
#pragma unroll
    for (int mt = 0; mt < 8; ++mt) acc[mt] = (f32x4){0.f, 0.f, 0.f, 0.f};

    const int r = tid >> 2;
    const int c16 = (tid & 3) * 16;
    const int swzw = (r & 7) << 4;
    char* wbase = (char*)As + r * 128;
    const int arow = lane & 15;
    const int swzr = (arow & 7) << 4;
    const int hi = (lane >> 4) * 16;

    for (int kc = 0; kc < 8; ++kc) {
        {
            const float* src = X + (size_t)(m0 + r) * 512 + kc * 64 + c16;
            const float4 v0 = *(const float4*)(src);
            const float4 v1 = *(const float4*)(src + 4);
            const float4 v2 = *(const float4*)(src + 8);
            const float4 v3 = *(const float4*)(src + 12);
            UV4H8 o0, o1;
            o0.e[0] = (f16)v0.x; o0.e[1] = (f16)v0.y; o0.e[2] = (f16)v0.z; o0.e[3] = (f16)v0.w;
            o0.e[4] = (f16)v1.x; o0.e[5] = (f16)v1.y; o0.e[6] = (f16)v1.z; o0.e[7] = (f16)v1.w;
            o1.e[0] = (f16)v2.x; o1.e[1] = (f16)v2.y; o1.e[2] = (f16)v2.z; o1.e[3] = (f16)v2.w;
            o1.e[4] = (f16)v3.x; o1.e[5] = (f16)v3.y; o1.e[6] = (f16)v3.z; o1.e[7] = (f16)v3.w;
            *(uint4*)(wbase + ((c16 * 2) ^ swzw)) = o0.u;
            *(uint4*)(wbase + ((c16 * 2 + 16) ^ swzw)) = o1.u;
        }
        __syncthreads();
#pragma unroll
        for (int mt = 0; mt < 8; ++mt) {
            const char* rbase = (const char*)As + (mt * 16 + arow) * 128;
            const f16x8 Af0 = *(const f16x8*)(rbase + ((hi) ^ swzr));
            acc[mt] = __builtin_amdgcn_mfma_f32_16x16x32_f16(Af0, Bf[kc * 2], acc[mt], 0, 0, 0);
            const f16x8 Af1 = *(const f16x8*)(rbase + ((64 + hi) ^ swzr));
            acc[mt] = __builtin_amdgcn_mfma_f32_16x16x32_f16(Af1, Bf[kc * 2 + 1], acc[mt], 0, 0, 0);
        }
        __syncthreads();
    }

    const int drow = (lane >> 4) * 4;
    if (tile < 32) {
        const int col = tile * 16 + tcol;
#pragma unroll
        for (int mt = 0; mt < 8; ++mt)
#pragma unroll
            for (int i = 0; i < 4; ++i)
                Pa[(size_t)(m0 + mt * 16 + drow + i) * 512 + col] = acc[mt][i] + bias;
    } else {
        const int col = (tile - 32) * 16 + tcol;
#pragma unroll
        for (int mt = 0; mt < 8; ++mt)
#pragma unroll
            for (int i = 0; i < 4; ++i)
                Pgh[(size_t)(m0 + mt * 16 + drow + i) * 512 + col] = (f16)(acc[mt][i] + bias);
    }
}

// ============================================================================
// Phase 2: recurrent scan v13 — scan12 structure, BALANCED: block = 16 rows x
// 128 cols (grid 32 = 8 rowgroups x 4 colblocks); ALL 8 waves carry one
// 16-col tile with BOTH gates (scan12-proven accumulation), in-register
// blend+publish, ONE barrier/step, 4-producer exchange group.
// ============================================================================
__global__ __launch_bounds__(512, 1) void scan13(
    const uint4* __restrict__ WP, const float* __restrict__ gamma,
    const float* __restrict__ beta, const float* __restrict__ Cvec,
    float* po, const f16* __restrict__ Pgh,
    u32* __restrict__ THex)   // [2][8][16][512] tagged u32
{
    __shared__ f16 hn[16][512];      // raw h̃, XOR-swizzled
    __shared__ float mu_s[16], rs_s[16];

    const int tid = threadIdx.x;
    const int wv = tid >> 6, lane = tid & 63;
    const int bid = blockIdx.x;
    const int rg = bid >> 2, cb = bid & 3;
    const int c0 = cb * 128, r0 = rg * 16;

    // ---- per-wave statics: both gates' fragments for one 16-col tile ----
    f16x8 Bfa[16], Bfg[16];
    {
        const int ta = cb * 8 + wv, tg_ = 32 + cb * 8 + wv;
#pragma unroll
        for (int kf = 0; kf < 16; ++kf) {
            UV4H8 ua; ua.u = WP[(size_t)(ta * 16 + kf) * 64 + lane];
            Bfa[kf] = ua.h;
            UV4H8 ug; ug.u = WP[(size_t)(tg_ * 16 + kf) * 64 + lane];
            Bfg[kf] = ug.h;
        }
    }
    const int mcol = c0 + wv * 16 + (lane & 15);
    const int dr = (lane >> 4) * 4;
    const float CaM = Cvec[mcol],        GaM = Cvec[512 + mcol];
    const float CgM = Cvec[1024 + mcol], GgM = Cvec[1536 + mcol];

    // ---- poll / rebuild / out-write roles ----
    const int rb = tid >> 5, u = tid & 31;
    const int colA = c0 + 2 * u;          // from v[2cb]
    const int colB = c0 + 64 + 2 * u;     // from v[2cb+1]
    const float gmA0 = gamma[colA], gmA1 = gamma[colA + 1];
    const float btA0 = beta[colA],  btA1 = beta[colA + 1];
    const float gmB0 = gamma[colB], gmB1 = gamma[colB + 1];
    const float btB0 = beta[colB],  btB1 = beta[colB + 1];
    const int arow = lane & 15;
    const int hi16 = (lane >> 4) * 16;
    const int swzr = (arow & 7) << 4;
    const int swzw = (rb & 7) << 4;
    const char* hrow_r = (const char*)&hn[arow][0];
    char* hrow_w = (char*)&hn[rb][0];
    const size_t prow = (size_t)(r0 + rb);

    const u64* pol0 = (const u64*)(THex + ((size_t)(0 * 8 + rg) * 16 + rb) * 512) + u;
    const u64* pol1 = (const u64*)(THex + ((size_t)(1 * 8 + rg) * 16 + rb) * 512) + u;

    // ---- t = 0: h0 = blend(pa, pg); publish tag 1, parity 0 ----
    {
#pragma unroll
        for (int i = 0; i < 4; ++i) {
            const size_t idx = ((size_t)(r0 + dr + i) * 512 + 0) * 512 + mcol;
            const float a0 = po[idx];
            const float g0 = (float)Pgh[idx];
            const float al = 1.f / (1.f + __expf(-g0));
            const float ac = fminf(fmaxf(a0, -15.f), 15.f);
            const float e = __expf(2.f * ac);
            const float th = (e - 1.f) / (e + 1.f);
            const float ht = al * (th - a0) + a0;
            H1 hb; hb.h = (f16)ht;
            st_u32g(THex + ((size_t)(0 * 8 + rg) * 16 + dr + i) * 512 + mcol,
                    (1u << 16) | (u32)hb.s);
        }
    }

    for (int t = 1; t < 512; ++t) {
        const unsigned tg = (unsigned)t;
        const u64* hp = ((t - 1) & 1) ? pol1 : pol0;

        // prefetch x-parts for this step (overlaps poll)
        float paM[4]; unsigned short pgM[4];
#pragma unroll
        for (int i = 0; i < 4; ++i) {
            const size_t idx = ((size_t)(r0 + dr + i) * 512 + (size_t)t) * 512 + mcol;
            paM[i] = po[idx];
            pgM[i] = *(const unsigned short*)(Pgh + idx);
        }

        // ---- branchless poll: 8 u64 (pairs of tagged u32) ----
        u64 v[8];
        for (;;) {
#pragma unroll
            for (int i = 0; i < 8; ++i) v[i] = ld_u64g(hp + i * 32);
            bool ok = true;
#pragma unroll
            for (int i = 0; i < 8; ++i)
                ok &= (((unsigned)(v[i] >> 16) & 0xFFFFu) == tg) &
                      ((unsigned)(v[i] >> 48) == tg);
            if (ok) break;
        }

        // ---- local stats of h̃(t-1) + swizzled hn rebuild ----
        float s1 = 0.f, s2 = 0.f;
#pragma unroll
        for (int i = 0; i < 8; ++i) {
            H1 a, b; a.s = (unsigned short)v[i]; b.s = (unsigned short)(v[i] >> 32);
            const float x0 = (float)a.h, x1 = (float)b.h;
            s1 += x0 + x1; s2 += x0 * x0 + x1 * x1;
            const u32 w32 = (u32)(v[i] & 0xFFFFu) | ((u32)(v[i] >> 32) << 16);
            *(u32*)(hrow_w + ((128 * i + 4 * u) ^ swzw)) = w32;
        }
#pragma unroll
        for (int m = 1; m < 32; m <<= 1) { s1 += __shfl_xor(s1, m); s2 += __shfl_xor(s2, m); }
        const float mu = s1 * (1.f / 512.f);
        const float var = s2 * (1.f / 512.f) - mu * mu;
        const float rs = rsqrtf(fmaxf(var, 0.f) + LN_EPS);
        if (u == 0) { mu_s[rb] = mu; rs_s[rb] = rs; }

        // ---- deferred out(t-1) for own 4 cols from polled slices ----
        {
            const size_t o = (prow * 512 + (size_t)(t - 1)) * 512;
            H1 a, b; a.s = (unsigned short)v[2 * cb]; b.s = (unsigned short)(v[2 * cb] >> 32);
            po[o + colA]     = ((float)a.h - mu) * rs * gmA0 + btA0;
            po[o + colA + 1] = ((float)b.h - mu) * rs * gmA1 + btA1;
            H1 c, d; c.s = (unsigned short)v[2 * cb + 1]; d.s = (unsigned short)(v[2 * cb + 1] >> 32);
            po[o + colB]     = ((float)c.h - mu) * rs * gmB0 + btB0;
            po[o + colB + 1] = ((float)d.h - mu) * rs * gmB1 + btB1;
        }
        __syncthreads();   // hn + mu_s ready (the ONLY barrier per step)

        // ---- MFMA (both gates, full-K acc pairs) + in-reg blend + publish ----
        {
            f32x4 acc0 = {0.f, 0.f, 0.f, 0.f};
            f32x4 acc1 = {0.f, 0.f, 0.f, 0.f};
            f32x4 acc2 = {0.f, 0.f, 0.f, 0.f};
            f32x4 acc3 = {0.f, 0.f, 0.f, 0.f};
#pragma unroll
            for (int kf = 0; kf < 8; ++kf) {
                const f16x8 Af0 = *(const f16x8*)(hrow_r + ((kf * 64 + hi16) ^ swzr));
                acc0 = __builtin_amdgcn_mfma_f32_16x16x32_f16(Af0, Bfa[kf], acc0, 0, 0, 0);
                acc2 = __builtin_amdgcn_mfma_f32_16x16x32_f16(Af0, Bfg[kf], acc2, 0, 0, 0);
                const f16x8 Af1 = *(const f16x8*)(hrow_r + (((kf + 8) * 64 + hi16) ^ swzr));
                acc1 = __builtin_amdgcn_mfma_f32_16x16x32_f16(Af1, Bfa[kf + 8], acc1, 0, 0, 0);
                acc3 = __builtin_amdgcn_mfma_f32_16x16x32_f16(Af1, Bfg[kf + 8], acc3, 0, 0, 0);
            }
            const u32 ptag = (u32)(t + 1) << 16;
            u32* pb = THex + ((size_t)((t & 1) * 8 + rg) * 16 + dr) * 512 + mcol;
#pragma unroll
            for (int i = 0; i < 4; ++i) {
                const float mui = mu_s[dr + i], rsi = rs_s[dr + i];
                const float mursi = mui * rsi;
                const float a0 = rsi * (acc0[i] + acc1[i]) - mursi * GaM + CaM + paM[i];
                H1 pgh; pgh.s = pgM[i];
                const float g0 = rsi * (acc2[i] + acc3[i]) - mursi * GgM + CgM + (float)pgh.h;
                const float al = 1.f / (1.f + __expf(-g0));
                const float ac = fminf(fmaxf(a0, -15.f), 15.f);
                const float e = __expf(2.f * ac);
                const float th = (e - 1.f) / (e + 1.f);
                const float nt = al * (th - a0) + a0;
                H1 hb; hb.h = (f16)nt;
                st_u32g(pb + (size_t)i * 512, ptag | (u32)hb.s);
            }
        }
        // no trailing barrier: next step's poll (covers ALL own waves' tags)
        // orders every cross-wave hn hazard.
    }

    // ---- tail: poll tag 512 (parity 1) -> out[.., 511, ..] ----
    {
        u64 v[8];
        for (;;) {
#pragma unroll
            for (int i = 0; i < 8; ++i) v[i] = ld_u64g(pol1 + i * 32);
            bool ok = true;
#pragma unroll
            for (int i = 0; i < 8; ++i)
                ok &= (((unsigned)(v[i] >> 16) & 0xFFFFu) == 512u) &
                      ((unsigned)(v[i] >> 48) == 512u);
            if (ok) break;
        }
        float s1 = 0.f, s2 = 0.f;
#pragma unroll
        for (int i = 0; i < 8; ++i) {
            H1 a, b; a.s = (unsigned short)v[i]; b.s = (unsigned short)(v[i] >> 32);
            const float x0 = (float)a.h, x1 = (float)b.h;
            s1 += x0 + x1; s2 += x0 * x0 + x1 * x1;
        }
#pragma unroll
        for (int m = 1; m < 32; m <<= 1) { s1 += __shfl_xor(s1, m); s2 += __shfl_xor(s2, m); }
        const float mu = s1 * (1.f / 512.f);
        const float var = s2 * (1.f / 512.f) - mu * mu;
        const float rs = rsqrtf(fmaxf(var, 0.f) + LN_EPS);
        const size_t o = (prow * 512 + 511) * 512;
        H1 a, b; a.s = (unsigned short)v[2 * cb]; b.s = (unsigned short)(v[2 * cb] >> 32);
        po[o + colA]     = ((float)a.h - mu) * rs * gmA0 + btA0;
        po[o + colA + 1] = ((float)b.h - mu) * rs * gmA1 + btA1;
        H1 c, d; c.s = (unsigned short)v[2 * cb + 1]; d.s = (unsigned short)(v[2 * cb + 1] >> 32);
        po[o + colB]     = ((float)c.h - mu) * rs * gmB0 + btB0;
        po[o + colB + 1] = ((float)d.h - mu) * rs * gmB1 + btB1;
    }
}

extern "C" void kernel_launch(void* const* d_in, const int* in_sizes, int n_in,
                              void* d_out, int out_size, void* d_ws, size_t ws_size,
                              hipStream_t stream) {
    (void)in_sizes; (void)n_in; (void)out_size; (void)ws_size;
    const float* X     = (const float*)d_in[0];
    const float* Wa    = (const float*)d_in[1];
    const float* Wg    = (const float*)d_in[2];
    const float* ba    = (const float*)d_in[3];
    const float* bg    = (const float*)d_in[4];
    const float* gamma = (const float*)d_in[5];
    const float* beta  = (const float*)d_in[6];
    float* out = (float*)d_out;

    char* ws = (char*)d_ws;
    f16*    Pgh  = (f16*)ws;                      // 67108864 B
    uint4*  WP   = (uint4*)(ws + 67108864);       // 1048576 B
    u32*    THex = (u32*)(ws + 68157440);         // 524288 B (131072 u32)
    float*  Cvec = (float*)(ws + 68681728);       // 8192 B
    uint4*  WPx  = (uint4*)(ws + 68689920);       // 1048576 B

    init_ex<<<dim3(256), dim3(256), 0, stream>>>((u64*)THex, 65536);
    pack_wfrags<<<dim3(256), dim3(256), 0, stream>>>(Wa, Wg, gamma, WP);
    pack_wx<<<dim3(256), dim3(256), 0, stream>>>(Wa, Wg, WPx);
    precompute_consts<<<dim3(512), dim3(64), 0, stream>>>(Wa, Wg, gamma, beta, Cvec);
    pgemm16<<<dim3(4096), dim3(512), 0, stream>>>(X, WPx, ba, bg, out, Pgh);

    void* args[] = { (void*)&WP, (void*)&gamma, (void*)&beta, (void*)&Cvec,
                     (void*)&out, (void*)&Pgh, (void*)&THex };
    hipLaunchCooperativeKernel((const void*)scan13, dim3(32), dim3(512),
                               args, 0, stream);
}

// Round 14
// 1490.417 us; speedup vs baseline: 1.4727x; 1.4727x over previous
//
#include <hip/hip_runtime.h>
#include <math.h>

typedef _Float16 f16;
typedef _Float16 f16x8 __attribute__((ext_vector_type(8)));
typedef float f32x4 __attribute__((ext_vector_type(4)));
typedef unsigned long long u64;
typedef unsigned u32;

union U32H2 { unsigned u; f16 h[2]; };
union UV4H8 { uint4 u; f16x8 h; f16 e[8]; };

#define LN_EPS 1e-5f

// ---- cache-bypassing (L3-coherent) 8-byte atomics, relaxed agent scope ----
__device__ __forceinline__ void st_u64g(u64* p, u64 v) {
    __hip_atomic_store(p, v, __ATOMIC_RELAXED, __HIP_MEMORY_SCOPE_AGENT);
}
__device__ __forceinline__ u64 ld_u64g(const u64* p) {
    return __hip_atomic_load(p, __ATOMIC_RELAXED, __HIP_MEMORY_SCOPE_AGENT);
}

// ============================================================================
// init: zero tagged-exchange buffer (every launch — replay safety)
// ============================================================================
__global__ __launch_bounds__(256) void init_ex(u64* p, int n) {
    const int i = blockIdx.x * 256 + threadIdx.x;
    if (i < n) p[i] = 0ull;
}

// ============================================================================
// Phase 0a: pack h-part weights (k<512), GAMMA-FOLDED, into B-fragment order.
//   col = (tile%32)*16 + (lane&15),  k = kf*32 + (lane>>4)*8 + j
// tiles 0..31 = a-gate, 32..63 = g-gate.
// ============================================================================
__global__ __launch_bounds__(256) void pack_wfrags(
    const float* __restrict__ Wa, const float* __restrict__ Wg,
    const float* __restrict__ gamma, uint4* __restrict__ WP)
{
    const int t = blockIdx.x * 256 + threadIdx.x;   // 0..65535
    const int lane = t & 63;
    const int kf = (t >> 6) & 15;
    const int tile = t >> 10;
    const float* W = (tile < 32) ? Wa : Wg;
    const int col = (tile & 31) * 16 + (lane & 15);
    const int k0 = kf * 32 + (lane >> 4) * 8;
    const float* src = W + (size_t)col * 1024 + k0;
    UV4H8 u;
#pragma unroll
    for (int j = 0; j < 8; ++j) u.e[j] = (f16)(src[j] * gamma[k0 + j]);
    WP[t] = u.u;
}

// ============================================================================
// Phase 0a': pack x-part weights (k 512..1023), NO fold, B-fragment order.
// ============================================================================
__global__ __launch_bounds__(256) void pack_wx(
    const float* __restrict__ Wa, const float* __restrict__ Wg,
    uint4* __restrict__ WPx)
{
    const int t = blockIdx.x * 256 + threadIdx.x;   // 0..65535
    const int lane = t & 63;
    const int kf = (t >> 6) & 15;
    const int tile = t >> 10;
    const float* W = (tile < 32) ? Wa : Wg;
    const int col = (tile & 31) * 16 + (lane & 15);
    const int k0 = kf * 32 + (lane >> 4) * 8;
    const float* src = W + (size_t)col * 1024 + 512 + k0;
    UV4H8 u;
#pragma unroll
    for (int j = 0; j < 8; ++j) u.e[j] = (f16)src[j];
    WPx[t] = u.u;
}

// ============================================================================
// Phase 0b: fold constants:
//   Cvec[0][o]=Wa[o]·beta  Cvec[1][o]=Wa[o]·gamma  Cvec[2][o]=Wg[o]·beta
//   Cvec[3][o]=Wg[o]·gamma   (h-part k<512, fp32)
// ============================================================================
__global__ __launch_bounds__(64) void precompute_consts(
    const float* __restrict__ Wa, const float* __restrict__ Wg,
    const float* __restrict__ gamma, const float* __restrict__ beta,
    float* __restrict__ Cvec)
{
    const int o = blockIdx.x;
    const int l = threadIdx.x;
    const float* wa = Wa + (size_t)o * 1024;
    const float* wg = Wg + (size_t)o * 1024;
    float ca = 0.f, ga = 0.f, cg = 0.f, gg = 0.f;
    for (int k = l; k < 512; k += 64) {
        const float bk = beta[k], gk = gamma[k], a = wa[k], g = wg[k];
        ca += a * bk; ga += a * gk; cg += g * bk; gg += g * gk;
    }
#pragma unroll
    for (int m = 1; m < 64; m <<= 1) {
        ca += __shfl_xor(ca, m); ga += __shfl_xor(ga, m);
        cg += __shfl_xor(cg, m); gg += __shfl_xor(gg, m);
    }
    if (l == 0) {
        Cvec[o] = ca; Cvec[512 + o] = ga; Cvec[1024 + o] = cg; Cvec[1536 + o] = gg;
    }
}

// ============================================================================
// Phase 1: precompute P = X @ Wx^T + bias — f16 MFMA (round-10 verified),
// now BOTH outputs f16 in ws: Pah (a-gate) + Pgh (g-gate). d_out untouched
// here; the scan writes every element of d_out.
// ============================================================================
__global__ __launch_bounds__(512) void pgemm16(
    const float* __restrict__ X, const uint4* __restrict__ WPx,
    const float* __restrict__ ba, const float* __restrict__ bg,
    f16* __restrict__ Pah, f16* __restrict__ Pgh)
{
    __shared__ f16 As[128 * 64];   // 16 KB, swizzled
    const int tid = threadIdx.x;
    const int wv = tid >> 6, lane = tid & 63;
    const int bid = blockIdx.x;
    const int bn = bid & 7;
    const int bm = bid >> 3;
    const int m0 = bm * 128;
    const int tile = bn * 8 + wv;

    f16x8 Bf[16];
#pragma unroll
    for (int kf = 0; kf < 16; ++kf) {
        UV4H8 uu; uu.u = WPx[(size_t)(tile * 16 + kf) * 64 + lane];
        Bf[kf] = uu.h;
    }
    const int tcol = lane & 15;
    const float bias = (tile < 32) ? ba[tile * 16 + tcol]
                                   : bg[(tile - 32) * 16 + tcol];

    f32x4 acc[8];
#pragma unroll
    for (int mt = 0; mt < 8; ++mt) acc[mt] = (f32x4){0.f, 0.f, 0.f, 0.f};

    const int r = tid >> 2;
    const int c16 = (tid & 3) * 16;
    const int swzw = (r & 7) << 4;
    char* wbase = (char*)As + r * 128;
    const int arow = lane & 15;
    const int swzr = (arow & 7) << 4;
    const int hi = (lane >> 4) * 16;

    for (int kc = 0; kc < 8; ++kc) {
        {
            const float* src = X + (size_t)(m0 + r) * 512 + kc * 64 + c16;
            const float4 v0 = *(const float4*)(src);
            const float4 v1 = *(const float4*)(src + 4);
            const float4 v2 = *(const float4*)(src + 8);
            const float4 v3 = *(const float4*)(src + 12);
            UV4H8 o0, o1;
            o0.e[0] = (f16)v0.x; o0.e[1] = (f16)v0.y; o0.e[2] = (f16)v0.z; o0.e[3] = (f16)v0.w;
            o0.e[4] = (f16)v1.x; o0.e[5] = (f16)v1.y; o0.e[6] = (f16)v1.z; o0.e[7] = (f16)v1.w;
            o1.e[0] = (f16)v2.x; o1.e[1] = (f16)v2.y; o1.e[2] = (f16)v2.z; o1.e[3] = (f16)v2.w;
            o1.e[4] = (f16)v3.x; o1.e[5] = (f16)v3.y; o1.e[6] = (f16)v3.z; o1.e[7] = (f16)v3.w;
            *(uint4*)(wbase + ((c16 * 2) ^ swzw)) = o0.u;
            *(uint4*)(wbase + ((c16 * 2 + 16) ^ swzw)) = o1.u;
        }
        __syncthreads();
#pragma unroll
        for (int mt = 0; mt < 8; ++mt) {
            const char* rbase = (const char*)As + (mt * 16 + arow) * 128;
            const f16x8 Af0 = *(const f16x8*)(rbase + ((hi) ^ swzr));
            acc[mt] = __builtin_amdgcn_mfma_f32_16x16x32_f16(Af0, Bf[kc * 2], acc[mt], 0, 0, 0);
            const f16x8 Af1 = *(const f16x8*)(rbase + ((64 + hi) ^ swzr));
            acc[mt] = __builtin_amdgcn_mfma_f32_16x16x32_f16(Af1, Bf[kc * 2 + 1], acc[mt], 0, 0, 0);
        }
        __syncthreads();
    }

    const int drow = (lane >> 4) * 4;
    if (tile < 32) {
        const int col = tile * 16 + tcol;
#pragma unroll
        for (int mt = 0; mt < 8; ++mt)
#pragma unroll
            for (int i = 0; i < 4; ++i)
                Pah[(size_t)(m0 + mt * 16 + drow + i) * 512 + col] = (f16)(acc[mt][i] + bias);
    } else {
        const int col = (tile - 32) * 16 + tcol;
#pragma unroll
        for (int mt = 0; mt < 8; ++mt)
#pragma unroll
            for (int i = 0; i < 4; ++i)
                Pgh[(size_t)(m0 + mt * 16 + drow + i) * 512 + col] = (f16)(acc[mt][i] + bias);
    }
}

// ============================================================================
// Phase 2: recurrent scan v14 — scan11 (1.32ms, best) with two safe edits:
//  (a) pa read from f16 Pah in ws (no more po read/write aliasing),
//  (b) stats shfl chain moved AFTER the Dx write (mu/rs consumed post-sync2;
//      MFMA issues ~150cy earlier per step). All else byte-frozen.
// ============================================================================
__global__ __launch_bounds__(512, 1) void scan14(
    const uint4* __restrict__ WP, const float* __restrict__ gamma,
    const float* __restrict__ beta, const float* __restrict__ Cvec,
    float* po, const f16* __restrict__ Pah, const f16* __restrict__ Pgh,
    u64* __restrict__ THex)   // [2][8][16][256] tagged (t+1)<<32 | 2xf16
{
    __shared__ f16 hn[16][512];      // raw h̃, XOR-swizzled
    __shared__ float Dx[16][132];    // MFMA D exchange

    const int tid = threadIdx.x;
    const int wv = tid >> 6, lane = tid & 63;
    const int bid = blockIdx.x;
    const int rg = bid >> 3, cb = bid & 7;
    const int c0 = cb * 64, r0 = rg * 16;

    const int tile = (wv < 4) ? (cb * 4 + wv) : (32 + cb * 4 + (wv - 4));
    f16x8 Bf[16];
#pragma unroll
    for (int kf = 0; kf < 16; ++kf) {
        UV4H8 uu; uu.u = WP[(size_t)(tile * 16 + kf) * 64 + lane];
        Bf[kf] = uu.h;
    }

    for (int i = tid; i < 16 * 256; i += 512) ((unsigned*)hn)[i] = 0u;

    const int rb = tid >> 5, u = tid & 31;
    const int col0 = c0 + 2 * u;
    const float Ca0 = Cvec[col0],        Ca1 = Cvec[col0 + 1];
    const float Ga0 = Cvec[512 + col0],  Ga1 = Cvec[512 + col0 + 1];
    const float Cg0 = Cvec[1024 + col0], Cg1 = Cvec[1024 + col0 + 1];
    const float Gg0 = Cvec[1536 + col0], Gg1 = Cvec[1536 + col0 + 1];
    const float gm0 = gamma[col0], gm1 = gamma[col0 + 1];
    const float bt0 = beta[col0],  bt1 = beta[col0 + 1];

    const int arow = lane & 15;
    const int hi16 = (lane >> 4) * 16;
    const int swzr = (arow & 7) << 4;
    const int swzw = (rb & 7) << 4;
    const char* hrow_r = (const char*)&hn[arow][0];
    char* hrow_w = (char*)&hn[rb][0];
    const int dr = (lane >> 4) * 4;
    const int dc = wv * 16 + (lane & 15);
    const size_t row = (size_t)(r0 + rb);

    u64* pub0 = THex + ((size_t)0 * 8 + rg) * 4096 + (size_t)rb * 256 + cb * 32 + u;
    u64* pub1 = THex + ((size_t)1 * 8 + rg) * 4096 + (size_t)rb * 256 + cb * 32 + u;
    const u64* pol0 = THex + ((size_t)0 * 8 + rg) * 4096 + (size_t)rb * 256 + u;
    const u64* pol1 = THex + ((size_t)1 * 8 + rg) * 4096 + (size_t)rb * 256 + u;

    float ht0, ht1;
    // ---- t = 0 ----
    {
        const size_t orow = (row * 512 + 0) * 512 + col0;
        U32H2 pa; pa.u = *(const unsigned*)(Pah + orow);
        U32H2 pg; pg.u = *(const unsigned*)(Pgh + orow);
        const float a0 = (float)pa.h[0], a1 = (float)pa.h[1];
        const float g0 = (float)pg.h[0], g1 = (float)pg.h[1];
        const float al0 = 1.f / (1.f + __expf(-g0));
        const float al1 = 1.f / (1.f + __expf(-g1));
        const float ac0 = fminf(fmaxf(a0, -15.f), 15.f);
        const float ac1 = fminf(fmaxf(a1, -15.f), 15.f);
        const float e0 = __expf(2.f * ac0), e1 = __expf(2.f * ac1);
        const float th0 = (e0 - 1.f) / (e0 + 1.f);
        const float th1 = (e1 - 1.f) / (e1 + 1.f);
        ht0 = al0 * (th0 - a0) + a0;
        ht1 = al1 * (th1 - a1) + a1;
        U32H2 hw; hw.h[0] = (f16)ht0; hw.h[1] = (f16)ht1;
        st_u64g(pub0, ((u64)1u << 32) | (u64)hw.u);
    }

    for (int t = 1; t < 512; ++t) {
        const unsigned tg = (unsigned)t;
        const u64* hp = ((t - 1) & 1) ? pol1 : pol0;
        const size_t orow = (row * 512 + (size_t)t) * 512 + col0;
        U32H2 pa; pa.u = *(const unsigned*)(Pah + orow);
        U32H2 pg; pg.u = *(const unsigned*)(Pgh + orow);

        // ---- branchless coalesced poll: all 8 u64 every iteration ----
        u64 v[8];
        for (;;) {
#pragma unroll
            for (int i = 0; i < 8; ++i) v[i] = ld_u64g(hp + i * 32);
            bool ok = true;
#pragma unroll
            for (int i = 0; i < 8; ++i) ok &= ((unsigned)(v[i] >> 32) == tg);
            if (ok) break;
        }

        // ---- per-thread stats partials + swizzled LDS rebuild ----
        float s1 = 0.f, s2 = 0.f;
#pragma unroll
        for (int i = 0; i < 8; ++i) {
            U32H2 hh; hh.u = (unsigned)v[i];
            const float x0 = (float)hh.h[0], x1 = (float)hh.h[1];
            s1 += x0 + x1; s2 += x0 * x0 + x1 * x1;
            *(u32*)(hrow_w + ((128 * i + 4 * u) ^ swzw)) = (unsigned)v[i];
        }
        __syncthreads();   // sync1: hn rebuilt

        // ---- MFMA FIRST (round-6 exact) — stats deferred past Dx write ----
        f32x4 acc0 = {0.f, 0.f, 0.f, 0.f};
        f32x4 acc1 = {0.f, 0.f, 0.f, 0.f};
#pragma unroll
        for (int kf = 0; kf < 8; ++kf) {
            const f16x8 Af0 = *(const f16x8*)(hrow_r + ((kf * 64 + hi16) ^ swzr));
            acc0 = __builtin_amdgcn_mfma_f32_16x16x32_f16(Af0, Bf[kf], acc0, 0, 0, 0);
            const f16x8 Af1 = *(const f16x8*)(hrow_r + (((kf + 8) * 64 + hi16) ^ swzr));
            acc1 = __builtin_amdgcn_mfma_f32_16x16x32_f16(Af1, Bf[kf + 8], acc1, 0, 0, 0);
        }
        Dx[dr + 0][dc] = acc0[0] + acc1[0];
        Dx[dr + 1][dc] = acc0[1] + acc1[1];
        Dx[dr + 2][dc] = acc0[2] + acc1[2];
        Dx[dr + 3][dc] = acc0[3] + acc1[3];

        // ---- stats shfl chain here: after Dx write, before sync2 ----
#pragma unroll
        for (int m = 1; m < 32; m <<= 1) { s1 += __shfl_xor(s1, m); s2 += __shfl_xor(s2, m); }
        const float mu = s1 * (1.f / 512.f);
        const float var = s2 * (1.f / 512.f) - mu * mu;
        const float rs = rsqrtf(fmaxf(var, 0.f) + LN_EPS);
        const float murs = mu * rs;
        __syncthreads();   // sync2: Dx ready

        // ---- scalar LN correction + gated blend (round-6 exact) ----
        const float a0 = rs * Dx[rb][2 * u]          - murs * Ga0 + Ca0 + (float)pa.h[0];
        const float a1 = rs * Dx[rb][2 * u + 1]      - murs * Ga1 + Ca1 + (float)pa.h[1];
        const float g0 = rs * Dx[rb][64 + 2 * u]     - murs * Gg0 + Cg0 + (float)pg.h[0];
        const float g1 = rs * Dx[rb][64 + 2 * u + 1] - murs * Gg1 + Cg1 + (float)pg.h[1];
        const float al0 = 1.f / (1.f + __expf(-g0));
        const float al1 = 1.f / (1.f + __expf(-g1));
        const float ac0 = fminf(fmaxf(a0, -15.f), 15.f);
        const float ac1 = fminf(fmaxf(a1, -15.f), 15.f);
        const float e0 = __expf(2.f * ac0), e1 = __expf(2.f * ac1);
        const float th0 = (e0 - 1.f) / (e0 + 1.f);
        const float th1 = (e1 - 1.f) / (e1 + 1.f);
        const float nt0 = al0 * (th0 - a0) + a0;
        const float nt1 = al1 * (th1 - a1) + a1;

        // ---- publish h̃_t FIRST (consumers' critical path) ----
        {
            U32H2 hw; hw.h[0] = (f16)nt0; hw.h[1] = (f16)nt1;
            st_u64g((t & 1) ? pub1 : pub0,
                    ((u64)(unsigned)(t + 1) << 32) | (u64)hw.u);
            po[orow - 512]     = (ht0 - mu) * rs * gm0 + bt0;
            po[orow - 512 + 1] = (ht1 - mu) * rs * gm1 + bt1;
            ht0 = nt0; ht1 = nt1;
        }
        __syncthreads();   // sync3 (round-6 proven)
    }

    // ---- tail: out[.., 511, ..] ----
    {
        u64 v[8];
        for (;;) {
#pragma unroll
            for (int i = 0; i < 8; ++i) v[i] = ld_u64g(pol1 + i * 32);
            bool ok = true;
#pragma unroll
            for (int i = 0; i < 8; ++i) ok &= ((unsigned)(v[i] >> 32) == 512u);
            if (ok) break;
        }
        float s1 = 0.f, s2 = 0.f;
#pragma unroll
        for (int i = 0; i < 8; ++i) {
            U32H2 hh; hh.u = (unsigned)v[i];
            const float x0 = (float)hh.h[0], x1 = (float)hh.h[1];
            s1 += x0 + x1; s2 += x0 * x0 + x1 * x1;
        }
#pragma unroll
        for (int m = 1; m < 32; m <<= 1) { s1 += __shfl_xor(s1, m); s2 += __shfl_xor(s2, m); }
        const float mu = s1 * (1.f / 512.f);
        const float var = s2 * (1.f / 512.f) - mu * mu;
        const float rs = rsqrtf(fmaxf(var, 0.f) + LN_EPS);
        const size_t orow = (row * 512 + 511) * 512 + col0;
        po[orow]     = (ht0 - mu) * rs * gm0 + bt0;
        po[orow + 1] = (ht1 - mu) * rs * gm1 + bt1;
    }
}

extern "C" void kernel_launch(void* const* d_in, const int* in_sizes, int n_in,
                              void* d_out, int out_size, void* d_ws, size_t ws_size,
                              hipStream_t stream) {
    (void)in_sizes; (void)n_in; (void)out_size; (void)ws_size;
    const float* X     = (const float*)d_in[0];
    const float* Wa    = (const float*)d_in[1];
    const float* Wg    = (const float*)d_in[2];
    const float* ba    = (const float*)d_in[3];
    const float* bg    = (const float*)d_in[4];
    const float* gamma = (const float*)d_in[5];
    const float* beta  = (const float*)d_in[6];
    float* out = (float*)d_out;

    char* ws = (char*)d_ws;
    f16*    Pgh  = (f16*)ws;                      // 67108864 B
    uint4*  WP   = (uint4*)(ws + 67108864);       // 1048576 B
    u64*    THex = (u64*)(ws + 68157440);         // 524288 B
    float*  Cvec = (float*)(ws + 68681728);       // 8192 B
    uint4*  WPx  = (uint4*)(ws + 68689920);       // 1048576 B
    f16*    Pah  = (f16*)(ws + 69738496);         // 67108864 B

    init_ex<<<dim3(256), dim3(256), 0, stream>>>(THex, 65536);
    pack_wfrags<<<dim3(256), dim3(256), 0, stream>>>(Wa, Wg, gamma, WP);
    pack_wx<<<dim3(256), dim3(256), 0, stream>>>(Wa, Wg, WPx);
    precompute_consts<<<dim3(512), dim3(64), 0, stream>>>(Wa, Wg, gamma, beta, Cvec);
    pgemm16<<<dim3(4096), dim3(512), 0, stream>>>(X, WPx, ba, bg, Pah, Pgh);

    void* args[] = { (void*)&WP, (void*)&gamma, (void*)&beta, (void*)&Cvec,
                     (void*)&out, (void*)&Pah, (void*)&Pgh, (void*)&THex };
    hipLaunchCooperativeKernel((const void*)scan14, dim3(64), dim3(512),
                               args, 0, stream);
}

// Round 15
// 1452.638 us; speedup vs baseline: 1.5110x; 1.0260x over previous
//
#include <hip/hip_runtime.h>
#include <math.h>

typedef _Float16 f16;
typedef _Float16 f16x8 __attribute__((ext_vector_type(8)));
typedef float f32x4 __attribute__((ext_vector_type(4)));
typedef unsigned long long u64;
typedef unsigned u32;

union U32H2 { unsigned u; f16 h[2]; };
union UV4H8 { uint4 u; f16x8 h; f16 e[8]; };

#define LN_EPS 1e-5f

// ---- cache-bypassing (L3-coherent) 8-byte atomics, relaxed agent scope ----
__device__ __forceinline__ void st_u64g(u64* p, u64 v) {
    __hip_atomic_store(p, v, __ATOMIC_RELAXED, __HIP_MEMORY_SCOPE_AGENT);
}
__device__ __forceinline__ u64 ld_u64g(const u64* p) {
    return __hip_atomic_load(p, __ATOMIC_RELAXED, __HIP_MEMORY_SCOPE_AGENT);
}

// ============================================================================
// init: zero tagged-exchange buffer (every launch — replay safety)
// ============================================================================
__global__ __launch_bounds__(256) void init_ex(u64* p, int n) {
    const int i = blockIdx.x * 256 + threadIdx.x;
    if (i < n) p[i] = 0ull;
}

// ============================================================================
// Phase 0a (merged): pack BOTH weight halves into B-fragment order.
//   bid < 256 : h-part (k<512), GAMMA-FOLDED -> WP
//   bid >= 256: x-part (k 512..1023), no fold -> WPx
//   col = (tile%32)*16 + (lane&15),  k = kf*32 + (lane>>4)*8 + j
// tiles 0..31 = a-gate, 32..63 = g-gate.
// ============================================================================
__global__ __launch_bounds__(256) void pack_all(
    const float* __restrict__ Wa, const float* __restrict__ Wg,
    const float* __restrict__ gamma, uint4* __restrict__ WP,
    uint4* __restrict__ WPx)
{
    const int bid = blockIdx.x;
    const bool isH = (bid < 256);
    const int t = (isH ? bid : (bid - 256)) * 256 + threadIdx.x;   // 0..65535
    const int lane = t & 63;
    const int kf = (t >> 6) & 15;
    const int tile = t >> 10;
    const float* W = (tile < 32) ? Wa : Wg;
    const int col = (tile & 31) * 16 + (lane & 15);
    const int k0 = kf * 32 + (lane >> 4) * 8;
    UV4H8 u;
    if (isH) {
        const float* src = W + (size_t)col * 1024 + k0;
#pragma unroll
        for (int j = 0; j < 8; ++j) u.e[j] = (f16)(src[j] * gamma[k0 + j]);
        WP[t] = u.u;
    } else {
        const float* src = W + (size_t)col * 1024 + 512 + k0;
#pragma unroll
        for (int j = 0; j < 8; ++j) u.e[j] = (f16)src[j];
        WPx[t] = u.u;
    }
}

// ============================================================================
// Phase 0b: fold constants:
//   Cvec[0][o]=Wa[o]·beta  Cvec[1][o]=Wa[o]·gamma  Cvec[2][o]=Wg[o]·beta
//   Cvec[3][o]=Wg[o]·gamma   (h-part k<512, fp32)
// ============================================================================
__global__ __launch_bounds__(64) void precompute_consts(
    const float* __restrict__ Wa, const float* __restrict__ Wg,
    const float* __restrict__ gamma, const float* __restrict__ beta,
    float* __restrict__ Cvec)
{
    const int o = blockIdx.x;
    const int l = threadIdx.x;
    const float* wa = Wa + (size_t)o * 1024;
    const float* wg = Wg + (size_t)o * 1024;
    float ca = 0.f, ga = 0.f, cg = 0.f, gg = 0.f;
    for (int k = l; k < 512; k += 64) {
        const float bk = beta[k], gk = gamma[k], a = wa[k], g = wg[k];
        ca += a * bk; ga += a * gk; cg += g * bk; gg += g * gk;
    }
#pragma unroll
    for (int m = 1; m < 64; m <<= 1) {
        ca += __shfl_xor(ca, m); ga += __shfl_xor(ga, m);
        cg += __shfl_xor(cg, m); gg += __shfl_xor(gg, m);
    }
    if (l == 0) {
        Cvec[o] = ca; Cvec[512 + o] = ga; Cvec[1024 + o] = cg; Cvec[1536 + o] = gg;
    }
}

// ============================================================================
// Phase 1: precompute P = X @ Wx^T + bias — f16 MFMA, DOUBLE-BUFFERED staging.
// Per K-chunk: issue next chunk's global loads BEFORE the MFMA chain, convert
// + LDS-write after, ONE barrier per chunk. Numerics identical to round 10.
// ============================================================================
__global__ __launch_bounds__(512) void pgemm16(
    const float* __restrict__ X, const uint4* __restrict__ WPx,
    const float* __restrict__ ba, const float* __restrict__ bg,
    f16* __restrict__ Pah, f16* __restrict__ Pgh)
{
    __shared__ f16 As[2][128 * 64];   // 2 x 16 KB, swizzled
    const int tid = threadIdx.x;
    const int wv = tid >> 6, lane = tid & 63;
    const int bid = blockIdx.x;
    const int bn = bid & 7;
    const int bm = bid >> 3;
    const int m0 = bm * 128;
    const int tile = bn * 8 + wv;

    f16x8 Bf[16];
#pragma unroll
    for (int kf = 0; kf < 16; ++kf) {
        UV4H8 uu; uu.u = WPx[(size_t)(tile * 16 + kf) * 64 + lane];
        Bf[kf] = uu.h;
    }
    const int tcol = lane & 15;
    const float bias = (tile < 32) ? ba[tile * 16 + tcol]
                                   : bg[(tile - 32) * 16 + tcol];

    f32x4 acc[8];
#pragma unroll
    for (int mt = 0; mt < 8; ++mt) acc[mt] = (f32x4){0.f, 0.f, 0.f, 0.f};

    const int r = tid >> 2;
    const int c16 = (tid & 3) * 16;
    const int swzw = (r & 7) << 4;
    const int arow = lane & 15;
    const int swzr = (arow & 7) << 4;
    const int hi = (lane >> 4) * 16;
    const float* xrow = X + (size_t)(m0 + r) * 512 + c16;

    // ---- prologue: stage chunk 0 into buffer 0 ----
    {
        const float4 v0 = *(const float4*)(xrow);
        const float4 v1 = *(const float4*)(xrow + 4);
        const float4 v2 = *(const float4*)(xrow + 8);
        const float4 v3 = *(const float4*)(xrow + 12);
        UV4H8 o0, o1;
        o0.e[0] = (f16)v0.x; o0.e[1] = (f16)v0.y; o0.e[2] = (f16)v0.z; o0.e[3] = (f16)v0.w;
        o0.e[4] = (f16)v1.x; o0.e[5] = (f16)v1.y; o0.e[6] = (f16)v1.z; o0.e[7] = (f16)v1.w;
        o1.e[0] = (f16)v2.x; o1.e[1] = (f16)v2.y; o1.e[2] = (f16)v2.z; o1.e[3] = (f16)v2.w;
        o1.e[4] = (f16)v3.x; o1.e[5] = (f16)v3.y; o1.e[6] = (f16)v3.z; o1.e[7] = (f16)v3.w;
        char* wb = (char*)&As[0][0] + r * 128;
        *(uint4*)(wb + ((c16 * 2) ^ swzw)) = o0.u;
        *(uint4*)(wb + ((c16 * 2 + 16) ^ swzw)) = o1.u;
    }
    __syncthreads();

    for (int kc = 0; kc < 8; ++kc) {
        const int cur = kc & 1;
        // ---- issue next chunk's global loads (latency hides under MFMA) ----
        float4 v0, v1, v2, v3;
        if (kc < 7) {
            const float* src = xrow + (kc + 1) * 64;
            v0 = *(const float4*)(src);
            v1 = *(const float4*)(src + 4);
            v2 = *(const float4*)(src + 8);
            v3 = *(const float4*)(src + 12);
        }
        // ---- compute on current buffer ----
#pragma unroll
        for (int mt = 0; mt < 8; ++mt) {
            const char* rbase = (const char*)&As[cur][0] + (mt * 16 + arow) * 128;
            const f16x8 Af0 = *(const f16x8*)(rbase + ((hi) ^ swzr));
            acc[mt] = __builtin_amdgcn_mfma_f32_16x16x32_f16(Af0, Bf[kc * 2], acc[mt], 0, 0, 0);
            const f16x8 Af1 = *(const f16x8*)(rbase + ((64 + hi) ^ swzr));
            acc[mt] = __builtin_amdgcn_mfma_f32_16x16x32_f16(Af1, Bf[kc * 2 + 1], acc[mt], 0, 0, 0);
        }
        // ---- convert + write next chunk into the other buffer ----
        if (kc < 7) {
            UV4H8 o0, o1;
            o0.e[0] = (f16)v0.x; o0.e[1] = (f16)v0.y; o0.e[2] = (f16)v0.z; o0.e[3] = (f16)v0.w;
            o0.e[4] = (f16)v1.x; o0.e[5] = (f16)v1.y; o0.e[6] = (f16)v1.z; o0.e[7] = (f16)v1.w;
            o1.e[0] = (f16)v2.x; o1.e[1] = (f16)v2.y; o1.e[2] = (f16)v2.z; o1.e[3] = (f16)v2.w;
            o1.e[4] = (f16)v3.x; o1.e[5] = (f16)v3.y; o1.e[6] = (f16)v3.z; o1.e[7] = (f16)v3.w;
            char* wb = (char*)&As[cur ^ 1][0] + r * 128;
            *(uint4*)(wb + ((c16 * 2) ^ swzw)) = o0.u;
            *(uint4*)(wb + ((c16 * 2 + 16) ^ swzw)) = o1.u;
        }
        __syncthreads();
    }

    const int drow = (lane >> 4) * 4;
    if (tile < 32) {
        const int col = tile * 16 + tcol;
#pragma unroll
        for (int mt = 0; mt < 8; ++mt)
#pragma unroll
            for (int i = 0; i < 4; ++i)
                Pah[(size_t)(m0 + mt * 16 + drow + i) * 512 + col] = (f16)(acc[mt][i] + bias);
    } else {
        const int col = (tile - 32) * 16 + tcol;
#pragma unroll
        for (int mt = 0; mt < 8; ++mt)
#pragma unroll
            for (int i = 0; i < 4; ++i)
                Pgh[(size_t)(m0 + mt * 16 + drow + i) * 512 + col] = (f16)(acc[mt][i] + bias);
    }
}

// ============================================================================
// Phase 2: recurrent scan — scan14 FROZEN (1.27 ms, absmax 0.03125):
// branchless all-8 poll, round-6 MFMA/blend arithmetic, stats after Dx write,
// f16 Pah/Pgh reads, publish-first, 3 barriers.
// ============================================================================
__global__ __launch_bounds__(512, 1) void scan14(
    const uint4* __restrict__ WP, const float* __restrict__ gamma,
    const float* __restrict__ beta, const float* __restrict__ Cvec,
    float* po, const f16* __restrict__ Pah, const f16* __restrict__ Pgh,
    u64* __restrict__ THex)   // [2][8][16][256] tagged (t+1)<<32 | 2xf16
{
    __shared__ f16 hn[16][512];      // raw h̃, XOR-swizzled
    __shared__ float Dx[16][132];    // MFMA D exchange

    const int tid = threadIdx.x;
    const int wv = tid >> 6, lane = tid & 63;
    const int bid = blockIdx.x;
    const int rg = bid >> 3, cb = bid & 7;
    const int c0 = cb * 64, r0 = rg * 16;

    const int tile = (wv < 4) ? (cb * 4 + wv) : (32 + cb * 4 + (wv - 4));
    f16x8 Bf[16];
#pragma unroll
    for (int kf = 0; kf < 16; ++kf) {
        UV4H8 uu; uu.u = WP[(size_t)(tile * 16 + kf) * 64 + lane];
        Bf[kf] = uu.h;
    }

    for (int i = tid; i < 16 * 256; i += 512) ((unsigned*)hn)[i] = 0u;

    const int rb = tid >> 5, u = tid & 31;
    const int col0 = c0 + 2 * u;
    const float Ca0 = Cvec[col0],        Ca1 = Cvec[col0 + 1];
    const float Ga0 = Cvec[512 + col0],  Ga1 = Cvec[512 + col0 + 1];
    const float Cg0 = Cvec[1024 + col0], Cg1 = Cvec[1024 + col0 + 1];
    const float Gg0 = Cvec[1536 + col0], Gg1 = Cvec[1536 + col0 + 1];
    const float gm0 = gamma[col0], gm1 = gamma[col0 + 1];
    const float bt0 = beta[col0],  bt1 = beta[col0 + 1];

    const int arow = lane & 15;
    const int hi16 = (lane >> 4) * 16;
    const int swzr = (arow & 7) << 4;
    const int swzw = (rb & 7) << 4;
    const char* hrow_r = (const char*)&hn[arow][0];
    char* hrow_w = (char*)&hn[rb][0];
    const int dr = (lane >> 4) * 4;
    const int dc = wv * 16 + (lane & 15);
    const size_t row = (size_t)(r0 + rb);

    u64* pub0 = THex + ((size_t)0 * 8 + rg) * 4096 + (size_t)rb * 256 + cb * 32 + u;
    u64* pub1 = THex + ((size_t)1 * 8 + rg) * 4096 + (size_t)rb * 256 + cb * 32 + u;
    const u64* pol0 = THex + ((size_t)0 * 8 + rg) * 4096 + (size_t)rb * 256 + u;
    const u64* pol1 = THex + ((size_t)1 * 8 + rg) * 4096 + (size_t)rb * 256 + u;

    float ht0, ht1;
    // ---- t = 0 ----
    {
        const size_t orow = (row * 512 + 0) * 512 + col0;
        U32H2 pa; pa.u = *(const unsigned*)(Pah + orow);
        U32H2 pg; pg.u = *(const unsigned*)(Pgh + orow);
        const float a0 = (float)pa.h[0], a1 = (float)pa.h[1];
        const float g0 = (float)pg.h[0], g1 = (float)pg.h[1];
        const float al0 = 1.f / (1.f + __expf(-g0));
        const float al1 = 1.f / (1.f + __expf(-g1));
        const float ac0 = fminf(fmaxf(a0, -15.f), 15.f);
        const float ac1 = fminf(fmaxf(a1, -15.f), 15.f);
        const float e0 = __expf(2.f * ac0), e1 = __expf(2.f * ac1);
        const float th0 = (e0 - 1.f) / (e0 + 1.f);
        const float th1 = (e1 - 1.f) / (e1 + 1.f);
        ht0 = al0 * (th0 - a0) + a0;
        ht1 = al1 * (th1 - a1) + a1;
        U32H2 hw; hw.h[0] = (f16)ht0; hw.h[1] = (f16)ht1;
        st_u64g(pub0, ((u64)1u << 32) | (u64)hw.u);
    }

    for (int t = 1; t < 512; ++t) {
        const unsigned tg = (unsigned)t;
        const u64* hp = ((t - 1) & 1) ? pol1 : pol0;
        const size_t orow = (row * 512 + (size_t)t) * 512 + col0;
        U32H2 pa; pa.u = *(const unsigned*)(Pah + orow);
        U32H2 pg; pg.u = *(const unsigned*)(Pgh + orow);

        // ---- branchless coalesced poll: all 8 u64 every iteration ----
        u64 v[8];
        for (;;) {
#pragma unroll
            for (int i = 0; i < 8; ++i) v[i] = ld_u64g(hp + i * 32);
            bool ok = true;
#pragma unroll
            for (int i = 0; i < 8; ++i) ok &= ((unsigned)(v[i] >> 32) == tg);
            if (ok) break;
        }

        // ---- per-thread stats partials + swizzled LDS rebuild ----
        float s1 = 0.f, s2 = 0.f;
#pragma unroll
        for (int i = 0; i < 8; ++i) {
            U32H2 hh; hh.u = (unsigned)v[i];
            const float x0 = (float)hh.h[0], x1 = (float)hh.h[1];
            s1 += x0 + x1; s2 += x0 * x0 + x1 * x1;
            *(u32*)(hrow_w + ((128 * i + 4 * u) ^ swzw)) = (unsigned)v[i];
        }
        __syncthreads();   // sync1: hn rebuilt

        // ---- MFMA FIRST (round-6 exact) — stats deferred past Dx write ----
        f32x4 acc0 = {0.f, 0.f, 0.f, 0.f};
        f32x4 acc1 = {0.f, 0.f, 0.f, 0.f};
#pragma unroll
        for (int kf = 0; kf < 8; ++kf) {
            const f16x8 Af0 = *(const f16x8*)(hrow_r + ((kf * 64 + hi16) ^ swzr));
            acc0 = __builtin_amdgcn_mfma_f32_16x16x32_f16(Af0, Bf[kf], acc0, 0, 0, 0);
            const f16x8 Af1 = *(const f16x8*)(hrow_r + (((kf + 8) * 64 + hi16) ^ swzr));
            acc1 = __builtin_amdgcn_mfma_f32_16x16x32_f16(Af1, Bf[kf + 8], acc1, 0, 0, 0);
        }
        Dx[dr + 0][dc] = acc0[0] + acc1[0];
        Dx[dr + 1][dc] = acc0[1] + acc1[1];
        Dx[dr + 2][dc] = acc0[2] + acc1[2];
        Dx[dr + 3][dc] = acc0[3] + acc1[3];

        // ---- stats shfl chain: after Dx write, before sync2 ----
#pragma unroll
        for (int m = 1; m < 32; m <<= 1) { s1 += __shfl_xor(s1, m); s2 += __shfl_xor(s2, m); }
        const float mu = s1 * (1.f / 512.f);
        const float var = s2 * (1.f / 512.f) - mu * mu;
        const float rs = rsqrtf(fmaxf(var, 0.f) + LN_EPS);
        const float murs = mu * rs;
        __syncthreads();   // sync2: Dx ready

        // ---- scalar LN correction + gated blend (round-6 exact) ----
        const float a0 = rs * Dx[rb][2 * u]          - murs * Ga0 + Ca0 + (float)pa.h[0];
        const float a1 = rs * Dx[rb][2 * u + 1]      - murs * Ga1 + Ca1 + (float)pa.h[1];
        const float g0 = rs * Dx[rb][64 + 2 * u]     - murs * Gg0 + Cg0 + (float)pg.h[0];
        const float g1 = rs * Dx[rb][64 + 2 * u + 1] - murs * Gg1 + Cg1 + (float)pg.h[1];
        const float al0 = 1.f / (1.f + __expf(-g0));
        const float al1 = 1.f / (1.f + __expf(-g1));
        const float ac0 = fminf(fmaxf(a0, -15.f), 15.f);
        const float ac1 = fminf(fmaxf(a1, -15.f), 15.f);
        const float e0 = __expf(2.f * ac0), e1 = __expf(2.f * ac1);
        const float th0 = (e0 - 1.f) / (e0 + 1.f);
        const float th1 = (e1 - 1.f) / (e1 + 1.f);
        const float nt0 = al0 * (th0 - a0) + a0;
        const float nt1 = al1 * (th1 - a1) + a1;

        // ---- publish h̃_t FIRST (consumers' critical path) ----
        {
            U32H2 hw; hw.h[0] = (f16)nt0; hw.h[1] = (f16)nt1;
            st_u64g((t & 1) ? pub1 : pub0,
                    ((u64)(unsigned)(t + 1) << 32) | (u64)hw.u);
            po[orow - 512]     = (ht0 - mu) * rs * gm0 + bt0;
            po[orow - 512 + 1] = (ht1 - mu) * rs * gm1 + bt1;
            ht0 = nt0; ht1 = nt1;
        }
        __syncthreads();   // sync3
    }

    // ---- tail: out[.., 511, ..] ----
    {
        u64 v[8];
        for (;;) {
#pragma unroll
            for (int i = 0; i < 8; ++i) v[i] = ld_u64g(pol1 + i * 32);
            bool ok = true;
#pragma unroll
            for (int i = 0; i < 8; ++i) ok &= ((unsigned)(v[i] >> 32) == 512u);
            if (ok) break;
        }
        float s1 = 0.f, s2 = 0.f;
#pragma unroll
        for (int i = 0; i < 8; ++i) {
            U32H2 hh; hh.u = (unsigned)v[i];
            const float x0 = (float)hh.h[0], x1 = (float)hh.h[1];
            s1 += x0 + x1; s2 += x0 * x0 + x1 * x1;
        }
#pragma unroll
        for (int m = 1; m < 32; m <<= 1) { s1 += __shfl_xor(s1, m); s2 += __shfl_xor(s2, m); }
        const float mu = s1 * (1.f / 512.f);
        const float var = s2 * (1.f / 512.f) - mu * mu;
        const float rs = rsqrtf(fmaxf(var, 0.f) + LN_EPS);
        const size_t orow = (row * 512 + 511) * 512 + col0;
        po[orow]     = (ht0 - mu) * rs * gm0 + bt0;
        po[orow + 1] = (ht1 - mu) * rs * gm1 + bt1;
    }
}

extern "C" void kernel_launch(void* const* d_in, const int* in_sizes, int n_in,
                              void* d_out, int out_size, void* d_ws, size_t ws_size,
                              hipStream_t stream) {
    (void)in_sizes; (void)n_in; (void)out_size; (void)ws_size;
    const float* X     = (const float*)d_in[0];
    const float* Wa    = (const float*)d_in[1];
    const float* Wg    = (const float*)d_in[2];
    const float* ba    = (const float*)d_in[3];
    const float* bg    = (const float*)d_in[4];
    const float* gamma = (const float*)d_in[5];
    const float* beta  = (const float*)d_in[6];
    float* out = (float*)d_out;

    char* ws = (char*)d_ws;
    f16*    Pgh  = (f16*)ws;                      // 67108864 B
    uint4*  WP   = (uint4*)(ws + 67108864);       // 1048576 B
    u64*    THex = (u64*)(ws + 68157440);         // 524288 B
    float*  Cvec = (float*)(ws + 68681728);       // 8192 B
    uint4*  WPx  = (uint4*)(ws + 68689920);       // 1048576 B
    f16*    Pah  = (f16*)(ws + 69738496);         // 67108864 B

    init_ex<<<dim3(256), dim3(256), 0, stream>>>(THex, 65536);
    pack_all<<<dim3(512), dim3(256), 0, stream>>>(Wa, Wg, gamma, WP, WPx);
    precompute_consts<<<dim3(512), dim3(64), 0, stream>>>(Wa, Wg, gamma, beta, Cvec);
    pgemm16<<<dim3(4096), dim3(512), 0, stream>>>(X, WPx, ba, bg, Pah, Pgh);

    void* args[] = { (void*)&WP, (void*)&gamma, (void*)&beta, (void*)&Cvec,
                     (void*)&out, (void*)&Pah, (void*)&Pgh, (void*)&THex };
    hipLaunchCooperativeKernel((const void*)scan14, dim3(64), dim3(512),
                               args, 0, stream);
}